// Round 9
// baseline (348.939 us; speedup 1.0000x reference)
//
#include <hip/hip_runtime.h>

// Causal linear attention — single persistent kernel, contention-free grid
// barrier (per-block arrival words + 64 spread go-flags, MAGIC-keyed so no
// initialization needed; d_ws is re-poisoned to 0xAA before every launch).
// Phases: cast -> fused bf16 MFMA GEMMs (q/k/v, fused softmax) -> chunk T_c
// -> exclusive prefix -> attention output. Grid 1024 blocks = 4/CU x 256 CU,
// co-resident by construction (launch_bounds(256,4), LDS 36.3KB <= 160/4).
// Co-residency + phase correctness HW-proven in rounds 6 and 8.

constexpr int DIM  = 1024;
constexpr int H    = 16;
constexpr int DH   = 64;
constexpr int LSEQ = 2048;
constexpr int NB   = 2;
constexpr int MTOK = NB * LSEQ;   // 4096 tokens
constexpr int CS   = 64;          // chunk size
constexpr int NC   = LSEQ / CS;   // 32 chunks
constexpr unsigned int NBLK = 1024;

typedef __bf16 bf16x8 __attribute__((ext_vector_type(8)));
typedef float floatx4 __attribute__((ext_vector_type(4)));
typedef unsigned short ushort_t;

__device__ __forceinline__ ushort_t f2bf(float f) {
  unsigned int u = __float_as_uint(f);
  u += 0x7FFFu + ((u >> 16) & 1u);   // RTNE
  return (ushort_t)(u >> 16);
}
__device__ __forceinline__ float bf2f(ushort_t b) {
  return __uint_as_float(((unsigned int)b) << 16);
}
__device__ __forceinline__ void async16(void* lds, const void* g) {
  __builtin_amdgcn_global_load_lds(
      (const __attribute__((address_space(1))) unsigned int*)g,
      (__attribute__((address_space(3))) unsigned int*)lds, 16, 0, 0);
}
__device__ __forceinline__ bf16x8 tfrag(const unsigned int* T, int row, int uoff) {
  union { bf16x8 v; unsigned int u[4]; } r;
  const unsigned int* p = T + row * 33 + uoff;
  r.u[0] = p[0]; r.u[1] = p[1]; r.u[2] = p[2]; r.u[3] = p[3];
  return r.v;
}
// transpose a 64x64 bf16 tile (global, row stride DIM) into stride-33-uint LDS
__device__ __forceinline__ void transpose_tile(const ushort_t* g, unsigned int* TT, int tid) {
  const int ic = tid & 7, tp = tid >> 3;
  const ushort_t* r0 = g + (size_t)(2 * tp) * DIM + ic * 8;
  union { uint4 q; ushort_t u[8]; } a0, a1;
  a0.q = *(const uint4*)r0;
  a1.q = *(const uint4*)(r0 + DIM);
#pragma unroll
  for (int j = 0; j < 8; j++)
    TT[(8 * ic + j) * 33 + tp] = (unsigned int)a0.u[j] | ((unsigned int)a1.u[j] << 16);
}

// ---- grid barrier k (0..3), zero-contention, no-init ------------------------
// region per k (3072 uints): arr[0..1023] one word per block; go flags at
// arr[1024 + g*32], g=0..63 (128B apart). Block b stores MAGIC+k to arr[b];
// block 0's 256 threads poll all 1024 words in parallel; then 64 lanes fan
// out MAGIC+k to the spread go flags; block b polls go[b&63]. 0xAA poison
// never equals MAGIC+k, so re-poison before each launch is the "reset".
__device__ __forceinline__ void gbar(unsigned int* bar, int k) {
  const unsigned int MAG = 0x51C0FFE0u + (unsigned int)k;
  unsigned int* arr = bar + (k * 3072);
  unsigned int* go  = arr + 1024;
  __syncthreads();
  if (blockIdx.x == 0) {
    if (threadIdx.x == 0) {
      __threadfence();
      __hip_atomic_store(&arr[0], MAG, __ATOMIC_RELAXED, __HIP_MEMORY_SCOPE_AGENT);
    }
#pragma unroll
    for (int it = 0; it < 4; it++) {
      unsigned int* p = &arr[threadIdx.x + it * 256];
      while (__hip_atomic_load(p, __ATOMIC_RELAXED, __HIP_MEMORY_SCOPE_AGENT) != MAG)
        __builtin_amdgcn_s_sleep(2);
    }
    __syncthreads();
    if (threadIdx.x < 64) {
      __threadfence();
      __hip_atomic_store(&go[threadIdx.x * 32], MAG, __ATOMIC_RELAXED,
                         __HIP_MEMORY_SCOPE_AGENT);
    }
  } else if (threadIdx.x == 0) {
    __threadfence();   // release this block's phase writes
    __hip_atomic_store(&arr[blockIdx.x], MAG, __ATOMIC_RELAXED,
                       __HIP_MEMORY_SCOPE_AGENT);
    unsigned int* myg = &go[(blockIdx.x & 63) * 32];
    while (__hip_atomic_load(myg, __ATOMIC_RELAXED, __HIP_MEMORY_SCOPE_AGENT) != MAG)
      __builtin_amdgcn_s_sleep(2);
    __threadfence();   // acquire: invalidate stale caches once
  }
  __syncthreads();
}

union SMem {
  struct { ushort_t A0[128 * 32]; ushort_t A1[128 * 32];
           ushort_t W0[128 * 32]; ushort_t W1[128 * 32]; } g;     // 32768 B
  ushort_t CsB[128 * 136];                                        // 34816 B
  struct { unsigned int KT[64 * 33]; unsigned int VT[64 * 33]; } ct;  // 16896 B
  struct { ushort_t Qs[64 * 72]; ushort_t Ks[64 * 72]; ushort_t Ts[64 * 72];
           unsigned int VT[64 * 33]; } at;                        // 36096 B
};

__global__ __launch_bounds__(256, 4) void fused_all(
    const float* __restrict__ query, const float* __restrict__ key,
    const float* __restrict__ Wq, const float* __restrict__ Wk,
    const float* __restrict__ Wv,
    ushort_t* __restrict__ qp, ushort_t* __restrict__ kp, ushort_t* __restrict__ vp,
    ushort_t* __restrict__ Tb, ushort_t* __restrict__ xbf, ushort_t* __restrict__ wbf,
    float* __restrict__ out, unsigned int* bar) {
  __shared__ SMem sm;
  const int bid = blockIdx.x;
  const int tid = threadIdx.x;
  const int lane = tid & 63, wid = tid >> 6;
  const int row16 = lane & 15, quad = lane >> 4;

  // ---- phase 0: cast fp32 -> bf16 ------------------------------------------
  {
    const int GX = (8 << 20) / 4;          // q+k float4 groups
    const int GW = (1 << 20) / 4;          // per-weight groups
    const int gtid = bid * 256 + tid;
    for (int i = gtid; i < GX; i += NBLK * 256) {
      const float4 f = (i < GX / 2) ? ((const float4*)query)[i]
                                    : ((const float4*)key)[i - GX / 2];
      ((ushort4*)xbf)[i] = make_ushort4(f2bf(f.x), f2bf(f.y), f2bf(f.z), f2bf(f.w));
    }
    for (int i = gtid; i < 3 * GW; i += NBLK * 256) {
      const float* w = (i < GW) ? Wq : ((i < 2 * GW) ? Wk : Wv);
      const int j = (i < GW) ? i : ((i < 2 * GW) ? i - GW : i - 2 * GW);
      const float4 f = ((const float4*)w)[j];
      ((ushort4*)wbf)[i] = make_ushort4(f2bf(f.x), f2bf(f.y), f2bf(f.z), f2bf(f.w));
    }
  }
  gbar(bar, 0);

  // ---- phase 1: fused GEMMs, tile 128x128, BK=64 (2 swizzled 32-k stages) --
  if (bid < 768) {
    const int z = bid >> 8;
    const int r = bid & 255;
    const int bn = (r & 7) * 128;
    const int bm = (r >> 3) * 128;
    const ushort_t* A = xbf + (z ? (size_t)(4 << 20) : 0);
    const ushort_t* W = wbf + (size_t)z * (1 << 20);
    ushort_t* C = (z == 0) ? qp : ((z == 1) ? kp : vp);
    const int wm = wid >> 1, wn = wid & 1;

    // staging: thread t covers chunk t (row t>>2) and t+256 (row t>>2 + 64);
    // fetches global chunk cg = c0 ^ ((row>>1)&3)  (same for row+64).
    const int row0 = tid >> 2, c0 = tid & 3;
    const int cg = c0 ^ ((row0 >> 1) & 3);
    const ushort_t* gA  = A + (size_t)(bm + row0) * DIM + cg * 8;
    const ushort_t* gA2 = gA + (size_t)64 * DIM;
    const ushort_t* gW  = W + (size_t)(bn + row0) * DIM + cg * 8;
    const ushort_t* gW2 = gW + (size_t)64 * DIM;

    floatx4 acc[4][4] = {};
    const int cq = quad ^ ((row16 >> 1) & 3);   // fragment-read swizzle

    for (int k0 = 0; k0 < DIM; k0 += 64) {
      __syncthreads();
      async16(sm.g.A0 + tid * 8, gA + k0);
      async16(sm.g.A0 + (tid + 256) * 8, gA2 + k0);
      async16(sm.g.A1 + tid * 8, gA + k0 + 32);
      async16(sm.g.A1 + (tid + 256) * 8, gA2 + k0 + 32);
      async16(sm.g.W0 + tid * 8, gW + k0);
      async16(sm.g.W0 + (tid + 256) * 8, gW2 + k0);
      async16(sm.g.W1 + tid * 8, gW + k0 + 32);
      async16(sm.g.W1 + (tid + 256) * 8, gW2 + k0 + 32);
      __syncthreads();
#pragma unroll
      for (int ks = 0; ks < 2; ks++) {
        const ushort_t* As = ks ? sm.g.A1 : sm.g.A0;
        const ushort_t* Ws = ks ? sm.g.W1 : sm.g.W0;
        bf16x8 a[4], b[4];
#pragma unroll
        for (int mt = 0; mt < 4; mt++)
          a[mt] = *(const bf16x8*)&As[(wm * 64 + mt * 16 + row16) * 32 + cq * 8];
#pragma unroll
        for (int nt = 0; nt < 4; nt++)
          b[nt] = *(const bf16x8*)&Ws[(wn * 64 + nt * 16 + row16) * 32 + cq * 8];
#pragma unroll
        for (int mt = 0; mt < 4; mt++)
#pragma unroll
          for (int nt = 0; nt < 4; nt++)
            acc[mt][nt] = __builtin_amdgcn_mfma_f32_16x16x32_bf16(a[mt], b[nt], acc[mt][nt], 0, 0, 0);
      }
    }
    __syncthreads();

    if (z < 2) {   // in-register per-head softmax (wave's 64 cols == one head)
#pragma unroll
      for (int mt = 0; mt < 4; mt++)
#pragma unroll
        for (int rr = 0; rr < 4; rr++) {
          float m = fmaxf(fmaxf(acc[mt][0][rr], acc[mt][1][rr]),
                          fmaxf(acc[mt][2][rr], acc[mt][3][rr]));
#pragma unroll
          for (int o = 1; o < 16; o <<= 1) m = fmaxf(m, __shfl_xor(m, o, 64));
          float e[4], s = 0.f;
#pragma unroll
          for (int nt = 0; nt < 4; nt++) { e[nt] = __expf(acc[mt][nt][rr] - m); s += e[nt]; }
#pragma unroll
          for (int o = 1; o < 16; o <<= 1) s += __shfl_xor(s, o, 64);
          const float inv = 1.f / s;
#pragma unroll
          for (int nt = 0; nt < 4; nt++) acc[mt][nt][rr] = e[nt] * inv;
        }
    }
#pragma unroll
    for (int mt = 0; mt < 4; mt++)
#pragma unroll
      for (int nt = 0; nt < 4; nt++)
#pragma unroll
        for (int rr = 0; rr < 4; rr++)
          sm.CsB[(wm * 64 + mt * 16 + quad * 4 + rr) * 136 + wn * 64 + nt * 16 + row16] =
              f2bf(acc[mt][nt][rr]);
    __syncthreads();
#pragma unroll
    for (int it = 0; it < 8; it++) {
      const int ch = tid + it * 256;        // 128 rows x 16 chunks
      const int row = ch >> 4, ic = ch & 15;
      const uint4 val = *(const uint4*)&sm.CsB[row * 136 + ic * 8];
      *(uint4*)&C[(size_t)(bm + row) * DIM + bn + ic * 8] = val;
    }
  }
  gbar(bar, 1);

  // ---- phase 2: T_c[j][i] = sum_t V[t][j] K[t][i] (MFMA, bf16 out) ---------
  {
    const int c = bid & 31, h = (bid >> 5) & 15, n = bid >> 9;
    const size_t gbase = ((size_t)(n * LSEQ + c * CS)) * DIM + h * DH;
    transpose_tile(kp + gbase, sm.ct.KT, tid);
    transpose_tile(vp + gbase, sm.ct.VT, tid);
    __syncthreads();
    floatx4 acc[4] = {};
#pragma unroll
    for (int ks = 0; ks < 2; ks++) {
      const bf16x8 a = tfrag(sm.ct.VT, wid * 16 + row16, ks * 16 + quad * 4);
#pragma unroll
      for (int nt = 0; nt < 4; nt++) {
        const bf16x8 b = tfrag(sm.ct.KT, nt * 16 + row16, ks * 16 + quad * 4);
        acc[nt] = __builtin_amdgcn_mfma_f32_16x16x32_bf16(a, b, acc[nt], 0, 0, 0);
      }
    }
    ushort_t* outp = Tb + ((size_t)((n * H + h) * NC + c)) * (DH * DH);
#pragma unroll
    for (int nt = 0; nt < 4; nt++)
#pragma unroll
      for (int rr = 0; rr < 4; rr++)
        outp[(wid * 16 + quad * 4 + rr) * DH + nt * 16 + row16] = f2bf(acc[nt][rr]);
  }
  gbar(bar, 2);

  // ---- phase 3: in-place exclusive prefix over chunks (fp32 scan) ----------
  if (bid < 512) {
    const int nh = bid >> 4;
    const int e  = (bid & 15) * 256 + tid;   // 0..4095
    ushort_t* b = Tb + (size_t)nh * NC * (DH * DH) + e;
    float run = 0.f;
#pragma unroll
    for (int c = 0; c < NC; c++) {
      const float cur = bf2f(b[(size_t)c * (DH * DH)]);
      b[(size_t)c * (DH * DH)] = f2bf(run);
      run += cur;
    }
  }
  gbar(bar, 3);

  // ---- phase 4: out = Q @ Tpre^T + tril(Q K^T) @ V (MFMA) ------------------
  {
    const int c = bid & 31, h = (bid >> 5) & 15, n = bid >> 9;
    const size_t gbase = ((size_t)(n * LSEQ + c * CS)) * DIM + h * DH;
    const size_t cbase = ((size_t)((n * H + h) * NC + c)) * (DH * DH);
#pragma unroll
    for (int it = 0; it < 2; it++) {
      const int ch = tid + it * 256;        // 0..511: 64 rows x 8 chunks
      const int row = ch >> 3, ic = ch & 7;
      *(uint4*)&sm.at.Qs[row * 72 + ic * 8] = *(const uint4*)&qp[gbase + (size_t)row * DIM + ic * 8];
      *(uint4*)&sm.at.Ks[row * 72 + ic * 8] = *(const uint4*)&kp[gbase + (size_t)row * DIM + ic * 8];
      *(uint4*)&sm.at.Ts[row * 72 + ic * 8] = *(const uint4*)&Tb[cbase + (size_t)row * DH + ic * 8];
    }
    transpose_tile(vp + gbase, sm.at.VT, tid);
    __syncthreads();

    const int t0 = wid * 16;
    floatx4 acc[4] = {};
    floatx4 pacc[4] = {};
#pragma unroll
    for (int ks = 0; ks < 2; ks++) {
      const bf16x8 aq = *(const bf16x8*)&sm.at.Qs[(t0 + row16) * 72 + ks * 32 + quad * 8];
#pragma unroll
      for (int nt = 0; nt < 4; nt++) {
        const bf16x8 bt = *(const bf16x8*)&sm.at.Ts[(nt * 16 + row16) * 72 + ks * 32 + quad * 8];
        acc[nt] = __builtin_amdgcn_mfma_f32_16x16x32_bf16(aq, bt, acc[nt], 0, 0, 0);
        const bf16x8 bk = *(const bf16x8*)&sm.at.Ks[(nt * 16 + row16) * 72 + ks * 32 + quad * 8];
        pacc[nt] = __builtin_amdgcn_mfma_f32_16x16x32_bf16(aq, bk, pacc[nt], 0, 0, 0);
      }
    }
    __syncthreads();   // all Ts reads done -> safe to reuse Ts as P buffer
#pragma unroll
    for (int nt = 0; nt < 4; nt++)
#pragma unroll
      for (int rr = 0; rr < 4; rr++) {
        const int t = t0 + quad * 4 + rr, s = nt * 16 + row16;
        sm.at.Ts[t * 72 + s] = f2bf((s <= t) ? pacc[nt][rr] : 0.f);
      }
    __syncthreads();
#pragma unroll
    for (int ks = 0; ks < 2; ks++) {
      const bf16x8 ap = *(const bf16x8*)&sm.at.Ts[(t0 + row16) * 72 + ks * 32 + quad * 8];
#pragma unroll
      for (int nt = 0; nt < 4; nt++) {
        const bf16x8 bv = tfrag(sm.at.VT, nt * 16 + row16, ks * 16 + quad * 4);
        acc[nt] = __builtin_amdgcn_mfma_f32_16x16x32_bf16(ap, bv, acc[nt], 0, 0, 0);
      }
    }
#pragma unroll
    for (int nt = 0; nt < 4; nt++)
#pragma unroll
      for (int rr = 0; rr < 4; rr++)
        out[gbase + (size_t)(t0 + quad * 4 + rr) * DIM + nt * 16 + row16] = acc[nt][rr];
  }
}

extern "C" void kernel_launch(void* const* d_in, const int* in_sizes, int n_in,
                              void* d_out, int out_size, void* d_ws, size_t ws_size,
                              hipStream_t stream) {
  const float* query = (const float*)d_in[0];
  const float* key   = (const float*)d_in[1];
  const float* Wq    = (const float*)d_in[2];
  const float* Wk    = (const float*)d_in[3];
  const float* Wv    = (const float*)d_in[4];
  float* out = (float*)d_out;

  // d_ws: [qp 8MB][kp 8MB][vp 8MB][Tb 8MB + 8MB scratch (xbf overlay 16MB)]
  //       [barrier region @48MB, 48KB — MAGIC-keyed, needs no init; harness
  //       re-poisons d_ws to 0xAA before every launch]. wbf (6MB) overlays
  //       d_out (dead until phase 4 rewrites it).
  ushort_t* qp  = (ushort_t*)d_ws;
  ushort_t* kp  = qp + (4 << 20);
  ushort_t* vp  = kp + (4 << 20);
  ushort_t* Tb  = vp + (4 << 20);
  ushort_t* xbf = Tb;                         // 16MB overlay (Tb + scratch)
  ushort_t* wbf = (ushort_t*)out;
  unsigned int* bar = (unsigned int*)((char*)d_ws + ((size_t)48 << 20));

  fused_all<<<dim3(NBLK), dim3(256), 0, stream>>>(
      query, key, Wq, Wk, Wv, qp, kp, vp, Tb, xbf, wbf, out, bar);
}

// Round 10
// 177.684 us; speedup vs baseline: 1.9638x; 1.9638x over previous
//
#include <hip/hip_runtime.h>

// Causal linear attention (chunked scan), bf16 MFMA end-to-end, 4 launches:
//  1) cast fp32->bf16   2) fused q/k/v GEMMs (BK=64, swizzled, fused softmax)
//  3) chunk_scan: per-(n,h) T_c = V_c^T K_c via MFMA + in-register exclusive
//     prefix over chunks (replaces chunk_T + prefix kernels)
//  4) attention: out = Q@Tpre^T + tril(QK^T)@V  (MFMA)
// Persistent-kernel variants (r6-r9) lose: device-scope fences cost ~45us
// per grid barrier (L2 writeback+invalidate), launch gaps are cheaper.

constexpr int DIM  = 1024;
constexpr int H    = 16;
constexpr int DH   = 64;
constexpr int LSEQ = 2048;
constexpr int NB   = 2;
constexpr int MTOK = NB * LSEQ;   // 4096 tokens
constexpr int CS   = 64;          // chunk size
constexpr int NC   = LSEQ / CS;   // 32 chunks

typedef __bf16 bf16x8 __attribute__((ext_vector_type(8)));
typedef float floatx4 __attribute__((ext_vector_type(4)));
typedef unsigned short ushort_t;

__device__ __forceinline__ ushort_t f2bf(float f) {
  unsigned int u = __float_as_uint(f);
  u += 0x7FFFu + ((u >> 16) & 1u);   // RTNE
  return (ushort_t)(u >> 16);
}
__device__ __forceinline__ float bf2f(ushort_t b) {
  return __uint_as_float(((unsigned int)b) << 16);
}
__device__ __forceinline__ void async16(void* lds, const void* g) {
  __builtin_amdgcn_global_load_lds(
      (const __attribute__((address_space(1))) unsigned int*)g,
      (__attribute__((address_space(3))) unsigned int*)lds, 16, 0, 0);
}
__device__ __forceinline__ bf16x8 tfrag(const unsigned int* T, int row, int uoff) {
  union { bf16x8 v; unsigned int u[4]; } r;
  const unsigned int* p = T + row * 33 + uoff;
  r.u[0] = p[0]; r.u[1] = p[1]; r.u[2] = p[2]; r.u[3] = p[3];
  return r.v;
}
// transpose a 64x64 bf16 tile (global, row stride DIM) into stride-33-uint LDS
__device__ __forceinline__ void transpose_tile(const ushort_t* g, unsigned int* TT, int tid) {
  const int ic = tid & 7, tp = tid >> 3;
  const ushort_t* r0 = g + (size_t)(2 * tp) * DIM + ic * 8;
  union { uint4 q; ushort_t u[8]; } a0, a1;
  a0.q = *(const uint4*)r0;
  a1.q = *(const uint4*)(r0 + DIM);
#pragma unroll
  for (int j = 0; j < 8; j++)
    TT[(8 * ic + j) * 33 + tp] = (unsigned int)a0.u[j] | ((unsigned int)a1.u[j] << 16);
}

// ------------- cast fp32 -> bf16 for query/key and the three weights --------
__global__ __launch_bounds__(256) void cast_all(const float* __restrict__ q,
                                                const float* __restrict__ k,
                                                const float* __restrict__ wq,
                                                const float* __restrict__ wk,
                                                const float* __restrict__ wv,
                                                ushort_t* __restrict__ xbf,
                                                ushort_t* __restrict__ wbf) {
  const int seg = blockIdx.y;
  const float* src;
  ushort_t* dst;
  int n4;
  if (seg == 0)      { src = q;  dst = xbf;                  n4 = (4 << 20) / 4; }
  else if (seg == 1) { src = k;  dst = xbf + (4 << 20);      n4 = (4 << 20) / 4; }
  else if (seg == 2) { src = wq; dst = wbf;                  n4 = (1 << 20) / 4; }
  else if (seg == 3) { src = wk; dst = wbf + (1 << 20);      n4 = (1 << 20) / 4; }
  else               { src = wv; dst = wbf + (2 << 20);      n4 = (1 << 20) / 4; }
  for (int i = blockIdx.x * 256 + threadIdx.x; i < n4; i += gridDim.x * 256) {
    const float4 f = ((const float4*)src)[i];
    ((ushort4*)dst)[i] = make_ushort4(f2bf(f.x), f2bf(f.y), f2bf(f.z), f2bf(f.w));
  }
}

// ----- fused bf16 MFMA GEMM NT: grid 768, z=bid>>8 in {q,k,v}; 128x128 tile,
// BK=64 (2 XOR-swizzled 32-k stages); in-register per-head softmax (z<2).
// Verified in rounds 8/9 (as persistent phase 1).
union GSm {
  struct { ushort_t A0[128 * 32]; ushort_t A1[128 * 32];
           ushort_t W0[128 * 32]; ushort_t W1[128 * 32]; } g;     // 32768 B
  ushort_t CsB[128 * 136];                                        // 34816 B
};

__global__ __launch_bounds__(256) void gemm_fused(const ushort_t* __restrict__ xbf,
                                                  const ushort_t* __restrict__ wbf,
                                                  ushort_t* __restrict__ qp,
                                                  ushort_t* __restrict__ kp,
                                                  ushort_t* __restrict__ vp) {
  __shared__ GSm sm;
  const int tid = threadIdx.x;
  const int z   = blockIdx.x >> 8;
  const int r   = blockIdx.x & 255;
  const int bn  = (r & 7) * 128;
  const int bm  = (r >> 3) * 128;
  const ushort_t* A = xbf + (z ? (size_t)(4 << 20) : 0);
  const ushort_t* W = wbf + (size_t)z * (1 << 20);
  ushort_t* C = (z == 0) ? qp : ((z == 1) ? kp : vp);
  const int lane = tid & 63, wid = tid >> 6;
  const int wm = wid >> 1, wn = wid & 1;
  const int row16 = lane & 15, quad = lane >> 4;

  const int row0 = tid >> 2, c0 = tid & 3;
  const int cg = c0 ^ ((row0 >> 1) & 3);
  const ushort_t* gA  = A + (size_t)(bm + row0) * DIM + cg * 8;
  const ushort_t* gA2 = gA + (size_t)64 * DIM;
  const ushort_t* gW  = W + (size_t)(bn + row0) * DIM + cg * 8;
  const ushort_t* gW2 = gW + (size_t)64 * DIM;

  floatx4 acc[4][4] = {};
  const int cq = quad ^ ((row16 >> 1) & 3);   // fragment-read swizzle

  for (int k0 = 0; k0 < DIM; k0 += 64) {
    __syncthreads();
    async16(sm.g.A0 + tid * 8, gA + k0);
    async16(sm.g.A0 + (tid + 256) * 8, gA2 + k0);
    async16(sm.g.A1 + tid * 8, gA + k0 + 32);
    async16(sm.g.A1 + (tid + 256) * 8, gA2 + k0 + 32);
    async16(sm.g.W0 + tid * 8, gW + k0);
    async16(sm.g.W0 + (tid + 256) * 8, gW2 + k0);
    async16(sm.g.W1 + tid * 8, gW + k0 + 32);
    async16(sm.g.W1 + (tid + 256) * 8, gW2 + k0 + 32);
    __syncthreads();
#pragma unroll
    for (int ks = 0; ks < 2; ks++) {
      const ushort_t* As = ks ? sm.g.A1 : sm.g.A0;
      const ushort_t* Ws = ks ? sm.g.W1 : sm.g.W0;
      bf16x8 a[4], b[4];
#pragma unroll
      for (int mt = 0; mt < 4; mt++)
        a[mt] = *(const bf16x8*)&As[(wm * 64 + mt * 16 + row16) * 32 + cq * 8];
#pragma unroll
      for (int nt = 0; nt < 4; nt++)
        b[nt] = *(const bf16x8*)&Ws[(wn * 64 + nt * 16 + row16) * 32 + cq * 8];
#pragma unroll
      for (int mt = 0; mt < 4; mt++)
#pragma unroll
        for (int nt = 0; nt < 4; nt++)
          acc[mt][nt] = __builtin_amdgcn_mfma_f32_16x16x32_bf16(a[mt], b[nt], acc[mt][nt], 0, 0, 0);
    }
  }
  __syncthreads();

  if (z < 2) {   // in-register per-head softmax (wave's 64 cols == one head)
#pragma unroll
    for (int mt = 0; mt < 4; mt++)
#pragma unroll
      for (int rr = 0; rr < 4; rr++) {
        float m = fmaxf(fmaxf(acc[mt][0][rr], acc[mt][1][rr]),
                        fmaxf(acc[mt][2][rr], acc[mt][3][rr]));
#pragma unroll
        for (int o = 1; o < 16; o <<= 1) m = fmaxf(m, __shfl_xor(m, o, 64));
        float e[4], s = 0.f;
#pragma unroll
        for (int nt = 0; nt < 4; nt++) { e[nt] = __expf(acc[mt][nt][rr] - m); s += e[nt]; }
#pragma unroll
        for (int o = 1; o < 16; o <<= 1) s += __shfl_xor(s, o, 64);
        const float inv = 1.f / s;
#pragma unroll
        for (int nt = 0; nt < 4; nt++) acc[mt][nt][rr] = e[nt] * inv;
      }
  }
#pragma unroll
  for (int mt = 0; mt < 4; mt++)
#pragma unroll
    for (int nt = 0; nt < 4; nt++)
#pragma unroll
      for (int rr = 0; rr < 4; rr++)
        sm.CsB[(wm * 64 + mt * 16 + quad * 4 + rr) * 136 + wn * 64 + nt * 16 + row16] =
            f2bf(acc[mt][nt][rr]);
  __syncthreads();
#pragma unroll
  for (int it = 0; it < 8; it++) {
    const int ch = tid + it * 256;        // 128 rows x 16 chunks
    const int row = ch >> 4, ic = ch & 15;
    const uint4 val = *(const uint4*)&sm.CsB[row * 136 + ic * 8];
    *(uint4*)&C[(size_t)(bm + row) * DIM + bn + ic * 8] = val;
  }
}

// ---- chunk_scan: per (n,h) block, for c=0..31: store exclusive prefix run
// (bf16) then T_c[j][i] = sum_t V[t][j] K[t][i] via MFMA, run += T_c.
// Fuses the former chunk_T + prefix kernels; prefix lives in registers in the
// MFMA C-layout (thread's 16 elements: row wid*16+quad*4+rr, col nt*16+row16).
__global__ __launch_bounds__(256) void chunk_scan(const ushort_t* __restrict__ kp,
                                                  const ushort_t* __restrict__ vp,
                                                  ushort_t* __restrict__ Tpre) {
  __shared__ unsigned int KT[64 * 33];
  __shared__ unsigned int VT[64 * 33];
  const int h = blockIdx.x & 15, n = blockIdx.x >> 4;
  const int tid = threadIdx.x;
  const int lane = tid & 63, wid = tid >> 6;
  const int row16 = lane & 15, quad = lane >> 4;

  floatx4 run[4] = {};
  for (int c = 0; c < NC; c++) {
    const size_t gbase = ((size_t)(n * LSEQ + c * CS)) * DIM + h * DH;
    __syncthreads();   // prior iteration's tfrag reads done before overwrite
    transpose_tile(kp + gbase, KT, tid);
    transpose_tile(vp + gbase, VT, tid);
    __syncthreads();

    // store exclusive prefix for this chunk (run == sum of T_0..T_{c-1})
    ushort_t* outp = Tpre + ((size_t)((n * H + h) * NC + c)) * (DH * DH);
#pragma unroll
    for (int nt = 0; nt < 4; nt++)
#pragma unroll
      for (int rr = 0; rr < 4; rr++)
        outp[(wid * 16 + quad * 4 + rr) * DH + nt * 16 + row16] = f2bf(run[nt][rr]);

    floatx4 acc[4] = {};
#pragma unroll
    for (int ks = 0; ks < 2; ks++) {
      const bf16x8 a = tfrag(VT, wid * 16 + row16, ks * 16 + quad * 4);
#pragma unroll
      for (int nt = 0; nt < 4; nt++) {
        const bf16x8 b = tfrag(KT, nt * 16 + row16, ks * 16 + quad * 4);
        acc[nt] = __builtin_amdgcn_mfma_f32_16x16x32_bf16(a, b, acc[nt], 0, 0, 0);
      }
    }
#pragma unroll
    for (int nt = 0; nt < 4; nt++) run[nt] += acc[nt];
  }
}

// ---- attention: out = Q @ Tpre^T + tril(Q K^T) @ V  (MFMA, fp32 out) -------
__global__ __launch_bounds__(256) void attn_mfma(const ushort_t* __restrict__ qp,
                                                 const ushort_t* __restrict__ kp,
                                                 const ushort_t* __restrict__ vp,
                                                 const ushort_t* __restrict__ csb,
                                                 float* __restrict__ out) {
  __shared__ ushort_t Qs[64 * 72];
  __shared__ ushort_t Ks[64 * 72];
  __shared__ ushort_t Ts[64 * 72];
  __shared__ unsigned int VT[64 * 33];
  const int c = blockIdx.x, h = blockIdx.y, n = blockIdx.z;
  const int tid = threadIdx.x;
  const size_t gbase = ((size_t)(n * LSEQ + c * CS)) * DIM + h * DH;
  const size_t cbase = ((size_t)((n * H + h) * NC + c)) * (DH * DH);

#pragma unroll
  for (int it = 0; it < 2; it++) {
    const int ch = tid + it * 256;        // 0..511: 64 rows x 8 chunks
    const int row = ch >> 3, ic = ch & 7;
    *(uint4*)&Qs[row * 72 + ic * 8] = *(const uint4*)&qp[gbase + (size_t)row * DIM + ic * 8];
    *(uint4*)&Ks[row * 72 + ic * 8] = *(const uint4*)&kp[gbase + (size_t)row * DIM + ic * 8];
    *(uint4*)&Ts[row * 72 + ic * 8] = *(const uint4*)&csb[cbase + (size_t)row * DH + ic * 8];
  }
  transpose_tile(vp + gbase, VT, tid);
  __syncthreads();

  const int lane = tid & 63, wid = tid >> 6;
  const int row16 = lane & 15, quad = lane >> 4;
  const int t0 = wid * 16;

  floatx4 acc[4] = {};
  floatx4 pacc[4] = {};
#pragma unroll
  for (int ks = 0; ks < 2; ks++) {
    const bf16x8 aq = *(const bf16x8*)&Qs[(t0 + row16) * 72 + ks * 32 + quad * 8];
#pragma unroll
    for (int nt = 0; nt < 4; nt++) {
      const bf16x8 bt = *(const bf16x8*)&Ts[(nt * 16 + row16) * 72 + ks * 32 + quad * 8];
      acc[nt] = __builtin_amdgcn_mfma_f32_16x16x32_bf16(aq, bt, acc[nt], 0, 0, 0);
      const bf16x8 bk = *(const bf16x8*)&Ks[(nt * 16 + row16) * 72 + ks * 32 + quad * 8];
      pacc[nt] = __builtin_amdgcn_mfma_f32_16x16x32_bf16(aq, bk, pacc[nt], 0, 0, 0);
    }
  }
  __syncthreads();   // all Ts reads done -> safe to reuse Ts as P buffer
#pragma unroll
  for (int nt = 0; nt < 4; nt++)
#pragma unroll
    for (int rr = 0; rr < 4; rr++) {
      const int t = t0 + quad * 4 + rr, s = nt * 16 + row16;
      Ts[t * 72 + s] = f2bf((s <= t) ? pacc[nt][rr] : 0.f);
    }
  __syncthreads();
#pragma unroll
  for (int ks = 0; ks < 2; ks++) {
    const bf16x8 ap = *(const bf16x8*)&Ts[(t0 + row16) * 72 + ks * 32 + quad * 8];
#pragma unroll
    for (int nt = 0; nt < 4; nt++) {
      const bf16x8 bv = tfrag(VT, nt * 16 + row16, ks * 16 + quad * 4);
      acc[nt] = __builtin_amdgcn_mfma_f32_16x16x32_bf16(ap, bv, acc[nt], 0, 0, 0);
    }
  }
#pragma unroll
  for (int nt = 0; nt < 4; nt++)
#pragma unroll
    for (int rr = 0; rr < 4; rr++)
      out[gbase + (size_t)(t0 + quad * 4 + rr) * DIM + nt * 16 + row16] = acc[nt][rr];
}

extern "C" void kernel_launch(void* const* d_in, const int* in_sizes, int n_in,
                              void* d_out, int out_size, void* d_ws, size_t ws_size,
                              hipStream_t stream) {
  const float* query = (const float*)d_in[0];
  const float* key   = (const float*)d_in[1];
  const float* Wq    = (const float*)d_in[2];
  const float* Wk    = (const float*)d_in[3];
  const float* Wv    = (const float*)d_in[4];
  float* out = (float*)d_out;

  // d_ws: [qp 8MB][kp 8MB][vp 8MB][Tpre 8MB + 8MB scratch (xbf overlay 16MB)]
  // wbf (6MB) overlays d_out (dead until attn_mfma rewrites it).
  // Launch order makes overlays safe: gemm reads xbf, then chunk_scan writes
  // Tpre (same region); gemm reads wbf, then attn writes out.
  ushort_t* qp   = (ushort_t*)d_ws;
  ushort_t* kp   = qp + (4 << 20);
  ushort_t* vp   = kp + (4 << 20);
  ushort_t* Tpre = vp + (4 << 20);
  ushort_t* xbf  = Tpre;                      // 16MB overlay (Tpre + scratch)
  ushort_t* wbf  = (ushort_t*)out;

  cast_all<<<dim3(512, 5), 256, 0, stream>>>(query, key, Wq, Wk, Wv, xbf, wbf);
  gemm_fused<<<dim3(768), 256, 0, stream>>>(xbf, wbf, qp, kp, vp);
  chunk_scan<<<dim3(NB * H), 256, 0, stream>>>(kp, vp, Tpre);
  attn_mfma<<<dim3(NC, H, NB), 256, 0, stream>>>(qp, kp, vp, Tpre, out);
}